// Round 8
// baseline (320.702 us; speedup 1.0000x reference)
//
#include <hip/hip_runtime.h>
#include <hip/hip_bf16.h>

#define DEPTH 16

typedef __attribute__((ext_vector_type(8))) short s8v;   // 8 x bf16
typedef __attribute__((ext_vector_type(4))) float f32x4; // MFMA acc

__device__ __forceinline__ float sigf(float x) { return 1.0f / (1.0f + __expf(-x)); }
__device__ __forceinline__ float tanh_fast(float x) { return 1.0f - 2.0f / (1.0f + __expf(2.0f * x)); }
__device__ __forceinline__ ushort f2bf(float f) {
    union { __hip_bfloat16 b; ushort u; } v; v.b = __float2bfloat16(f); return v.u;
}
__device__ __forceinline__ float bf2f(ushort u) {
    union { float f; unsigned int i; } v; v.i = ((unsigned int)u) << 16; return v.f;
}

// ---------------- prepass: pack weights + fused bias + bf16 embedding gather + bar reset ----------------
// Bpack: (((bn*12 + kk)*4 + seg)*128 + nl)*8 + t, col order nl -> g=(nl>>4)&3,
// j = bn*32 + (nl>>6)*16 + (nl&15)  => after MFMA each lane holds all 4 gates of one j.
__global__ __launch_bounds__(256) void prepass(
    const int* __restrict__ nt, const float* __restrict__ na,
    const float* __restrict__ emb,
    const float* __restrict__ Wih, const float* __restrict__ Whh,
    const float* __restrict__ bih, const float* __restrict__ bhh,
    ushort* __restrict__ Bpack, float* __restrict__ bsum,
    ushort* __restrict__ xall, int* __restrict__ bar)
{
    const int gid = blockIdx.x * 256 + threadIdx.x;
    if (gid < 16) bar[gid] = 0;
    if (gid < 24576) {
        const int nl  = gid & 127;
        const int seg = (gid >> 7) & 3;
        const int rest = gid >> 9;
        const int kk = rest % 12;
        const int bn = rest / 12;
        const int g  = (nl >> 4) & 3;
        const int j  = bn * 32 + ((nl >> 6) << 4) + (nl & 15);
        const int row = g * 256 + j;
        const int k = kk * 32 + seg * 8;
        const float* src = (k < 128) ? (Wih + (size_t)row * 128 + k)
                                     : (Whh + (size_t)row * 256 + (k - 128));
        float4 w0 = *(const float4*)(src);
        float4 w1 = *(const float4*)(src + 4);
        ushort o[8] = { f2bf(w0.x), f2bf(w0.y), f2bf(w0.z), f2bf(w0.w),
                        f2bf(w1.x), f2bf(w1.y), f2bf(w1.z), f2bf(w1.w) };
        *(s8v*)(Bpack + (size_t)gid * 8) = *(const s8v*)o;
    }
    if (gid < 512) {
        const int row = (gid >> 7) * 256 + (gid & 127);
        bsum[gid] = bih[row] + bhh[row];
    }
    const int node = gid >> 4;
    const int run  = gid & 15;
    if (node < 65535) {
        const int ty = nt[node];
        const float* src = emb + (size_t)ty * 128 + run * 8;
        float4 w0 = *(const float4*)src;
        float4 w1 = *(const float4*)(src + 4);
        if (run == 15 && (ty == 1 || ty == 2)) w1.w = na[node];
        ushort o[8] = { f2bf(w0.x), f2bf(w0.y), f2bf(w0.z), f2bf(w0.w),
                        f2bf(w1.x), f2bf(w1.y), f2bf(w1.z), f2bf(w1.w) };
        *(s8v*)(xall + (size_t)node * 128 + run * 8) = *(const s8v*)o;
    }
}

// ---------------- two-level pair kernel (levels 15..12) ----------------
__global__ __launch_bounds__(512) void pair_gemm(
    const ushort* __restrict__ xall,
    const ushort* __restrict__ Bpack, const float* __restrict__ bsum,
    const ushort* __restrict__ h_in, const float* __restrict__ c_in,
    ushort* __restrict__ h_out, float* __restrict__ c_out,
    int startC, int startP, int nP, int has_h)
{
    __shared__ __align__(16) ushort hC[64][136];
    __shared__ float cC[32][132];

    const int tid  = threadIdx.x;
    const int lane = tid & 63;
    const int wave = tid >> 6;
    const int lc = lane & 15, seg = lane >> 4;
    const int koff = seg * 8;
    const int nC = 2 * nP;
    const int b = blockIdx.x;

    // ===== stage 1: children, M=64, N=512 =====
    {
        const int wm2 = wave >> 2;
        const int bn  = wave & 3;
        const ushort* px[2];
        const ushort* ph[2][2];
        #pragma unroll
        for (int mi = 0; mi < 2; ++mi) {
            int mloc = wm2 * 32 + mi * 16 + lc;
            int cg = 64 * b + mloc;
            int cgc = cg < nC ? cg : nC - 1;
            px[mi]    = xall + (size_t)(startC + cgc) * 128 + koff;
            ph[mi][0] = h_in + (size_t)(2 * cgc) * 128 + koff;
            ph[mi][1] = h_in + (size_t)(2 * cgc + 1) * 128 + koff;
        }
        const ushort* pb = Bpack + (size_t)bn * 49152 + (size_t)seg * 1024
                                 + (size_t)lc * 8;

        f32x4 acc[2][8];
        #pragma unroll
        for (int mi = 0; mi < 2; ++mi)
            #pragma unroll
            for (int f = 0; f < 8; ++f) acc[mi][f] = (f32x4){0.f, 0.f, 0.f, 0.f};

        #pragma unroll
        for (int kk = 0; kk < 4; ++kk) {
            s8v a0 = *(const s8v*)(px[0] + kk * 32);
            s8v a1 = *(const s8v*)(px[1] + kk * 32);
            #pragma unroll
            for (int f = 0; f < 8; ++f) {
                s8v bb = *(const s8v*)(pb + (size_t)kk * 4096 + f * 128);
                acc[0][f] = __builtin_amdgcn_mfma_f32_16x16x32_bf16(a0, bb, acc[0][f], 0, 0, 0);
                acc[1][f] = __builtin_amdgcn_mfma_f32_16x16x32_bf16(a1, bb, acc[1][f], 0, 0, 0);
            }
        }
        if (has_h) {
            #pragma unroll
            for (int kk = 0; kk < 8; ++kk) {
                const int hi = kk >> 2, off = (kk & 3) * 32;
                s8v a0 = *(const s8v*)(ph[0][hi] + off);
                s8v a1 = *(const s8v*)(ph[1][hi] + off);
                #pragma unroll
                for (int f = 0; f < 8; ++f) {
                    s8v bb = *(const s8v*)(pb + (size_t)(kk + 4) * 4096 + f * 128);
                    acc[0][f] = __builtin_amdgcn_mfma_f32_16x16x32_bf16(a0, bb, acc[0][f], 0, 0, 0);
                    acc[1][f] = __builtin_amdgcn_mfma_f32_16x16x32_bf16(a1, bb, acc[1][f], 0, 0, 0);
                }
            }
        }
        #pragma unroll
        for (int bh = 0; bh < 2; ++bh) {
            const int j = bn * 32 + bh * 16 + lc;
            const float bi = bsum[j];
            const float bf = bsum[128 + j];
            const float bg = bsum[256 + j];
            const float bo = bsum[384 + j];
            #pragma unroll
            for (int mi = 0; mi < 2; ++mi) {
                #pragma unroll
                for (int r = 0; r < 4; ++r) {
                    const int mloc = wm2 * 32 + mi * 16 + seg * 4 + r;
                    const int cg = 64 * b + mloc;
                    if (cg < nC) {
                        const float gi = acc[mi][bh * 4 + 0][r] + bi;
                        const float gf = acc[mi][bh * 4 + 1][r] + bf;
                        const float gg = acc[mi][bh * 4 + 2][r] + bg;
                        const float go = acc[mi][bh * 4 + 3][r] + bo;
                        const float c0 = has_h ? c_in[(size_t)cg * 128 + j] : 0.0f;
                        const float cn = sigf(gf) * c0 + sigf(gi) * tanh_fast(gg);
                        const float hn = sigf(go) * tanh_fast(cn);
                        hC[mloc][j] = f2bf(hn);
                        if (!(mloc & 1)) cC[mloc >> 1][j] = cn;
                    }
                }
            }
        }
    }
    __syncthreads();

    // ===== stage 2: parents, M=32, N=512 =====
    {
        const int bn = wave >> 1;
        const int wn = wave & 1;
        const ushort* px[2];
        int mcl[2];
        #pragma unroll
        for (int mi = 0; mi < 2; ++mi) {
            int m = mi * 16 + lc;
            int mPg = 32 * b + m;
            int mc = mPg < nP ? mPg : nP - 1;
            mcl[mi] = mc - 32 * b;
            px[mi] = xall + (size_t)(startP + mc) * 128 + koff;
        }
        const ushort* pb = Bpack + (size_t)bn * 49152 + (size_t)seg * 1024
                                 + (size_t)(wn * 64 + lc) * 8;

        f32x4 acc[2][4];
        #pragma unroll
        for (int mi = 0; mi < 2; ++mi)
            #pragma unroll
            for (int f = 0; f < 4; ++f) acc[mi][f] = (f32x4){0.f, 0.f, 0.f, 0.f};

        #pragma unroll
        for (int kk = 0; kk < 4; ++kk) {
            s8v a0 = *(const s8v*)(px[0] + kk * 32);
            s8v a1 = *(const s8v*)(px[1] + kk * 32);
            #pragma unroll
            for (int f = 0; f < 4; ++f) {
                s8v bb = *(const s8v*)(pb + (size_t)kk * 4096 + f * 128);
                acc[0][f] = __builtin_amdgcn_mfma_f32_16x16x32_bf16(a0, bb, acc[0][f], 0, 0, 0);
                acc[1][f] = __builtin_amdgcn_mfma_f32_16x16x32_bf16(a1, bb, acc[1][f], 0, 0, 0);
            }
        }
        #pragma unroll
        for (int kk = 0; kk < 8; ++kk) {
            const int hi = kk >> 2, off = (kk & 3) * 32;
            s8v a0 = *(const s8v*)(&hC[2 * mcl[0] + hi][off + koff]);
            s8v a1 = *(const s8v*)(&hC[2 * mcl[1] + hi][off + koff]);
            #pragma unroll
            for (int f = 0; f < 4; ++f) {
                s8v bb = *(const s8v*)(pb + (size_t)(kk + 4) * 4096 + f * 128);
                acc[0][f] = __builtin_amdgcn_mfma_f32_16x16x32_bf16(a0, bb, acc[0][f], 0, 0, 0);
                acc[1][f] = __builtin_amdgcn_mfma_f32_16x16x32_bf16(a1, bb, acc[1][f], 0, 0, 0);
            }
        }

        const int j = bn * 32 + wn * 16 + lc;
        const float bi = bsum[j];
        const float bf = bsum[128 + j];
        const float bg = bsum[256 + j];
        const float bo = bsum[384 + j];
        #pragma unroll
        for (int mi = 0; mi < 2; ++mi) {
            #pragma unroll
            for (int r = 0; r < 4; ++r) {
                const int m = mi * 16 + seg * 4 + r;
                const int mPg = 32 * b + m;
                if (mPg < nP) {
                    const float gi = acc[mi][0][r] + bi;
                    const float gf = acc[mi][1][r] + bf;
                    const float gg = acc[mi][2][r] + bg;
                    const float go = acc[mi][3][r] + bo;
                    const float c0 = cC[m][j];
                    const float cn = sigf(gf) * c0 + sigf(gi) * tanh_fast(gg);
                    const float hn = sigf(go) * tanh_fast(cn);
                    h_out[(size_t)mPg * 128 + j] = f2bf(hn);
                    if (!(mPg & 1)) c_out[(size_t)(mPg >> 1) * 128 + j] = cn;
                }
            }
        }
    }
}

// ---------------- persistent finisher: levels 11..0 + head, 32 blocks + device barrier ----------------
// Block (bn = blockIdx.x&3, chunk = blockIdx.x>>2). Per level: block computes rows
// [chunk*128, ...) stride 1024 of its 128 eff cols (bn slice). Fresh output buffer per level.
// hT[lvl] elem offset (4096 - (2<<lvl))*128 ushorts; cT[lvl] offset (4096 - (2<<lvl))*64 floats.
__global__ __launch_bounds__(512) void tree_finish(
    const ushort* __restrict__ xall,
    const ushort* __restrict__ Bpack, const float* __restrict__ bsum,
    const ushort* __restrict__ h12, const float* __restrict__ c12,
    ushort* __restrict__ tailh, float* __restrict__ tailc, int* __restrict__ bar,
    const float* __restrict__ W1, const float* __restrict__ b1,
    const float* __restrict__ W2, const float* __restrict__ b2,
    const float* __restrict__ vmask, float* __restrict__ out)
{
    __shared__ float hs[128];
    __shared__ float as[128];

    const int tid  = threadIdx.x;
    const int lane = tid & 63;
    const int wave = tid >> 6;
    const int wn = wave & 1;        // f-half
    const int mt = wave >> 1;       // 0..3 m-subtile of 32 rows
    const int lc = lane & 15, seg = lane >> 4;
    const int koff = seg * 8;
    const int bn = blockIdx.x & 3;
    const int chunk = blockIdx.x >> 2;

    const ushort* pb = Bpack + (size_t)bn * 49152 + (size_t)seg * 1024
                             + (size_t)(wn * 64 + lc) * 8;
    const int j = bn * 32 + wn * 16 + lc;
    const float bi = bsum[j];
    const float bfv = bsum[128 + j];
    const float bg = bsum[256 + j];
    const float bo = bsum[384 + j];

    for (int lvl = 11; lvl >= 0; --lvl) {
        const int nP = 1 << lvl;
        const int nA = (nP >> 7) > 0 ? ((nP >> 7) < 8 ? (nP >> 7) : 8) : 1;  // active chunks
        if (chunk >= nA) return;    // this block is done forever (its data already released)
        const int startP = nP - 1;

        const ushort* hc; const float* cc;
        if (lvl == 11) { hc = h12; cc = c12; }
        else {
            hc = tailh + (size_t)(4096 - (2 << (lvl + 1))) * 128;
            cc = tailc + (size_t)(4096 - (2 << (lvl + 1))) * 64;
        }
        ushort* ho = tailh + (size_t)(4096 - (2 << lvl)) * 128;
        float*  co = tailc + (size_t)(4096 - (2 << lvl)) * 64;

        for (int m0 = chunk * 128; m0 < nP; m0 += 1024) {
            const ushort* px[2];
            const ushort* phh[2][2];
            #pragma unroll
            for (int mi = 0; mi < 2; ++mi) {
                int m = m0 + mt * 32 + mi * 16 + lc;
                int mc = m < nP ? m : nP - 1;
                px[mi]     = xall + (size_t)(startP + mc) * 128 + koff;
                phh[mi][0] = hc + (size_t)(2 * mc) * 128 + koff;
                phh[mi][1] = hc + (size_t)(2 * mc + 1) * 128 + koff;
            }
            f32x4 acc[2][4];
            #pragma unroll
            for (int mi = 0; mi < 2; ++mi)
                #pragma unroll
                for (int f = 0; f < 4; ++f) acc[mi][f] = (f32x4){0.f, 0.f, 0.f, 0.f};

            #pragma unroll
            for (int kk = 0; kk < 4; ++kk) {
                s8v a0 = *(const s8v*)(px[0] + kk * 32);
                s8v a1 = *(const s8v*)(px[1] + kk * 32);
                #pragma unroll
                for (int f = 0; f < 4; ++f) {
                    s8v bb = *(const s8v*)(pb + (size_t)kk * 4096 + f * 128);
                    acc[0][f] = __builtin_amdgcn_mfma_f32_16x16x32_bf16(a0, bb, acc[0][f], 0, 0, 0);
                    acc[1][f] = __builtin_amdgcn_mfma_f32_16x16x32_bf16(a1, bb, acc[1][f], 0, 0, 0);
                }
            }
            #pragma unroll
            for (int kk = 0; kk < 8; ++kk) {
                const int hi = kk >> 2, off = (kk & 3) * 32;
                s8v a0 = *(const s8v*)(phh[0][hi] + off);
                s8v a1 = *(const s8v*)(phh[1][hi] + off);
                #pragma unroll
                for (int f = 0; f < 4; ++f) {
                    s8v bb = *(const s8v*)(pb + (size_t)(kk + 4) * 4096 + f * 128);
                    acc[0][f] = __builtin_amdgcn_mfma_f32_16x16x32_bf16(a0, bb, acc[0][f], 0, 0, 0);
                    acc[1][f] = __builtin_amdgcn_mfma_f32_16x16x32_bf16(a1, bb, acc[1][f], 0, 0, 0);
                }
            }

            #pragma unroll
            for (int mi = 0; mi < 2; ++mi) {
                #pragma unroll
                for (int r = 0; r < 4; ++r) {
                    const int m = m0 + mt * 32 + mi * 16 + seg * 4 + r;
                    if (m < nP) {
                        const float gi = acc[mi][0][r] + bi;
                        const float gf = acc[mi][1][r] + bfv;
                        const float gg = acc[mi][2][r] + bg;
                        const float go = acc[mi][3][r] + bo;
                        const float c0 = cc[(size_t)m * 128 + j];
                        const float cn = sigf(gf) * c0 + sigf(gi) * tanh_fast(gg);
                        const float hn = sigf(go) * tanh_fast(cn);
                        ho[(size_t)m * 128 + j] = f2bf(hn);
                        if (!(m & 1)) co[(size_t)(m >> 1) * 128 + j] = cn;
                    }
                }
            }
        }

        // device-scope barrier among the 4*nA participating blocks
        __syncthreads();
        if (tid == 0) {
            __hip_atomic_fetch_add(&bar[lvl], 1, __ATOMIC_RELEASE, __HIP_MEMORY_SCOPE_AGENT);
            while (__hip_atomic_load(&bar[lvl], __ATOMIC_ACQUIRE, __HIP_MEMORY_SCOPE_AGENT) < 4 * nA)
                __builtin_amdgcn_s_sleep(2);
        }
        __syncthreads();
        __threadfence();
    }

    // ---- head on block 0 (root h at tailh offset (4096-2)*128) ----
    if (blockIdx.x == 0) {
        const ushort* hroot = tailh + (size_t)4094 * 128;
        if (tid < 128) hs[tid] = bf2f(hroot[tid]);
        __syncthreads();
        if (tid < 128) {
            float a1 = b1[tid];
            #pragma unroll 4
            for (int k = 0; k < 128; ++k) a1 = fmaf(hs[k], W1[tid * 128 + k], a1);
            as[tid] = fmaxf(a1, 0.0f);
        }
        __syncthreads();
        if (tid < 32) {
            float l = b2[tid];
            #pragma unroll 4
            for (int k = 0; k < 128; ++k) l = fmaf(as[k], W2[tid * 128 + k], l);
            l = (l + logf(vmask[tid])) * (1.0f / 3.0f);
            float mx = l;
            #pragma unroll
            for (int o = 16; o >= 1; o >>= 1) mx = fmaxf(mx, __shfl_xor(mx, o, 32));
            const float e = __expf(l - mx);
            float s = e;
            #pragma unroll
            for (int o = 16; o >= 1; o >>= 1) s += __shfl_xor(s, o, 32);
            out[tid] = e / s;
        }
    }
}

extern "C" void kernel_launch(void* const* d_in, const int* in_sizes, int n_in,
                              void* d_out, int out_size, void* d_ws, size_t ws_size,
                              hipStream_t stream)
{
    const int*   node_types = (const int*)  d_in[0];
    const float* node_args  = (const float*)d_in[1];
    const float* vmask      = (const float*)d_in[2];
    const float* emb        = (const float*)d_in[3];
    const float* Wih        = (const float*)d_in[4];
    const float* Whh        = (const float*)d_in[5];
    const float* bih        = (const float*)d_in[6];
    const float* bhh        = (const float*)d_in[7];
    const float* W1         = (const float*)d_in[8];
    const float* b1         = (const float*)d_in[9];
    const float* W2         = (const float*)d_in[10];
    const float* b2         = (const float*)d_in[11];

    char* w = (char*)d_ws;
    ushort* xall  = (ushort*)(w);                 // 16,777,216
    ushort* Bpack = (ushort*)(w + 16777216);      // 393,216
    float*  bsum  = (float*) (w + 17170432);      // 2,048
    ushort* hA    = (ushort*)(w + 17172480);      // level-14 h: 16384*128*2 = 4,194,304
    float*  cA    = (float*) (w + 21366784);      // level-14 c: 8192*128*4  = 4,194,304
    ushort* hB    = (ushort*)(w + 25561088);      // level-12 h: 4096*128*2  = 1,048,576
    float*  cB    = (float*) (w + 26609664);      // level-12 c: 2048*128*4  = 1,048,576
    ushort* tailh = (ushort*)(w + 27658240);      // ~1 MB (levels 11..0 h)
    float*  tailc = (float*) (w + 28706816);      // ~1 MB (levels 11..0 c)
    int*    bar   = (int*)   (w + 29755392);      // 64 B

    prepass<<<4096, 256, 0, stream>>>(node_types, node_args, emb,
                                      Wih, Whh, bih, bhh, Bpack, bsum, xall, bar);

    // (C,P) = (15,14) leaf -> A ; (13,12) A -> B
    pair_gemm<<<512, 512, 0, stream>>>(xall, Bpack, bsum, hB, cB, hA, cA, 32767, 16383, 16384, 0);
    pair_gemm<<<128, 512, 0, stream>>>(xall, Bpack, bsum, hA, cA, hB, cB,  8191,  4095,  4096, 1);

    // levels 11..0 + head in one persistent kernel
    tree_finish<<<32, 512, 0, stream>>>(xall, Bpack, bsum, hB, cB,
                                        tailh, tailc, bar,
                                        W1, b1, W2, b2, vmask, (float*)d_out);
}

// Round 9
// 312.979 us; speedup vs baseline: 1.0247x; 1.0247x over previous
//
#include <hip/hip_runtime.h>
#include <hip/hip_bf16.h>

typedef __attribute__((ext_vector_type(8))) short s8v;   // 8 x bf16
typedef __attribute__((ext_vector_type(4))) float f32x4; // MFMA acc

__device__ __forceinline__ float sigf(float x) { return 1.0f / (1.0f + __expf(-x)); }
__device__ __forceinline__ float tanh_fast(float x) { return 1.0f - 2.0f / (1.0f + __expf(2.0f * x)); }
__device__ __forceinline__ ushort f2bf(float f) {
    union { __hip_bfloat16 b; ushort u; } v; v.b = __float2bfloat16(f); return v.u;
}
__device__ __forceinline__ float bf2f(ushort u) {
    union { float f; unsigned int i; } v; v.i = ((unsigned int)u) << 16; return v.f;
}

// ---------------- prepass: pack weights + fused bias + bf16 embedding gather ----------------
// Bpack: (((bn*12 + kk)*4 + seg)*128 + nl)*8 + t, col order nl -> g=(nl>>4)&3,
// j = bn*32 + (nl>>6)*16 + (nl&15)  => after MFMA each lane holds all 4 gates of one j.
__global__ __launch_bounds__(256) void prepass(
    const int* __restrict__ nt, const float* __restrict__ na,
    const float* __restrict__ emb,
    const float* __restrict__ Wih, const float* __restrict__ Whh,
    const float* __restrict__ bih, const float* __restrict__ bhh,
    ushort* __restrict__ Bpack, float* __restrict__ bsum,
    ushort* __restrict__ xall)
{
    const int gid = blockIdx.x * 256 + threadIdx.x;
    if (gid < 24576) {
        const int nl  = gid & 127;
        const int seg = (gid >> 7) & 3;
        const int rest = gid >> 9;
        const int kk = rest % 12;
        const int bn = rest / 12;
        const int g  = (nl >> 4) & 3;
        const int j  = bn * 32 + ((nl >> 6) << 4) + (nl & 15);
        const int row = g * 256 + j;
        const int k = kk * 32 + seg * 8;
        const float* src = (k < 128) ? (Wih + (size_t)row * 128 + k)
                                     : (Whh + (size_t)row * 256 + (k - 128));
        float4 w0 = *(const float4*)(src);
        float4 w1 = *(const float4*)(src + 4);
        ushort o[8] = { f2bf(w0.x), f2bf(w0.y), f2bf(w0.z), f2bf(w0.w),
                        f2bf(w1.x), f2bf(w1.y), f2bf(w1.z), f2bf(w1.w) };
        *(s8v*)(Bpack + (size_t)gid * 8) = *(const s8v*)o;
    }
    if (gid < 512) {
        const int row = (gid >> 7) * 256 + (gid & 127);
        bsum[gid] = bih[row] + bhh[row];
    }
    const int node = gid >> 4;
    const int run  = gid & 15;
    if (node < 65535) {
        const int ty = nt[node];
        const float* src = emb + (size_t)ty * 128 + run * 8;
        float4 w0 = *(const float4*)src;
        float4 w1 = *(const float4*)(src + 4);
        if (run == 15 && (ty == 1 || ty == 2)) w1.w = na[node];
        ushort o[8] = { f2bf(w0.x), f2bf(w0.y), f2bf(w0.z), f2bf(w0.w),
                        f2bf(w1.x), f2bf(w1.y), f2bf(w1.z), f2bf(w1.w) };
        *(s8v*)(xall + (size_t)node * 128 + run * 8) = *(const s8v*)o;
    }
}

// ---------------- quad kernel: 4 consecutive levels, B resident (VGPR+LDS) ----------------
// Block owns a subtree slice: at level L it computes rows [b*npb, (b+1)*npb), npb = n_l/grid.
// 8 waves: wave w -> (bn=w>>1, wn=w&1) = 64 eff cols (16 j x 4 gates), full K.
// B frags: kk 0..7 in VGPR (128 regs), kk 8..11 in LDS (128KB).
// h_all[node]: bf16 h by global heap node id. c_all[p]: fp32 c of node 2p+1 (left child of p).
template<bool LEAF, bool HEAD>
__global__ __launch_bounds__(512, 1) void quad(
    const ushort* __restrict__ xall,
    const ushort* __restrict__ Bpack, const float* __restrict__ bsum,
    ushort* __restrict__ h_all, float* __restrict__ c_all,
    int lvl_top,
    const float* __restrict__ W1, const float* __restrict__ b1,
    const float* __restrict__ W2, const float* __restrict__ b2,
    const float* __restrict__ vmask, float* __restrict__ out)
{
    __shared__ __align__(16) ushort BL[8 * 16 * 64 * 8];   // 128 KB
    __shared__ float hs[128];
    __shared__ float as[128];

    const int tid  = threadIdx.x;
    const int lane = tid & 63;
    const int w    = tid >> 6;
    const int bn = w >> 1, wn = w & 1;
    const int lc = lane & 15, seg = lane >> 4;
    const int koff = seg * 8;

    // ---- load B fragments (once) ----
    const ushort* pb = Bpack + (size_t)bn * 49152 + (size_t)seg * 1024
                             + (size_t)(wn * 64 + lc) * 8;
    s8v bv[8][4];
    #pragma unroll
    for (int kk = 0; kk < 8; ++kk)
        #pragma unroll
        for (int f = 0; f < 4; ++f)
            bv[kk][f] = *(const s8v*)(pb + (size_t)kk * 4096 + f * 128);
    #pragma unroll
    for (int kk = 8; kk < 12; ++kk)
        #pragma unroll
        for (int f = 0; f < 4; ++f) {
            s8v t = *(const s8v*)(pb + (size_t)kk * 4096 + f * 128);
            *(s8v*)(&BL[(((size_t)w * 16 + (kk - 8) * 4 + f) * 64 + lane) * 8]) = t;
        }

    const int j = bn * 32 + wn * 16 + lc;
    const float bi  = bsum[j];
    const float bf_ = bsum[128 + j];
    const float bg  = bsum[256 + j];
    const float bo  = bsum[384 + j];

    for (int L = lvl_top; L > lvl_top - 4; --L) {
        const int n_l = 1 << L;
        const int start = n_l - 1;
        int npb = n_l / (int)gridDim.x;
        if (npb < 1) npb = 1;
        const int rb = blockIdx.x * npb;
        const bool leaf_lvl = LEAF && (L == lvl_top);

        for (int m0 = 0; m0 < npb; m0 += 32) {
            int gA[2];
            #pragma unroll
            for (int mi = 0; mi < 2; ++mi) {
                int mloc = m0 + mi * 16 + lc;
                int mc = mloc < npb ? mloc : npb - 1;
                gA[mi] = start + rb + mc;
            }
            const ushort* px0 = xall + (size_t)gA[0] * 128 + koff;
            const ushort* px1 = xall + (size_t)gA[1] * 128 + koff;

            f32x4 acc[2][4];
            #pragma unroll
            for (int mi = 0; mi < 2; ++mi)
                #pragma unroll
                for (int f = 0; f < 4; ++f) acc[mi][f] = (f32x4){0.f, 0.f, 0.f, 0.f};

            // K part 1: x (kk 0..3, VGPR B)
            #pragma unroll
            for (int kk = 0; kk < 4; ++kk) {
                s8v a0 = *(const s8v*)(px0 + kk * 32);
                s8v a1 = *(const s8v*)(px1 + kk * 32);
                #pragma unroll
                for (int f = 0; f < 4; ++f) {
                    acc[0][f] = __builtin_amdgcn_mfma_f32_16x16x32_bf16(a0, bv[kk][f], acc[0][f], 0, 0, 0);
                    acc[1][f] = __builtin_amdgcn_mfma_f32_16x16x32_bf16(a1, bv[kk][f], acc[1][f], 0, 0, 0);
                }
            }
            if (!leaf_lvl) {
                const ushort* ph00 = h_all + (size_t)(2 * gA[0] + 1) * 128 + koff;
                const ushort* ph01 = h_all + (size_t)(2 * gA[0] + 2) * 128 + koff;
                const ushort* ph10 = h_all + (size_t)(2 * gA[1] + 1) * 128 + koff;
                const ushort* ph11 = h_all + (size_t)(2 * gA[1] + 2) * 128 + koff;
                // K part 2: left child h (kk 4..7, VGPR B)
                #pragma unroll
                for (int kk = 4; kk < 8; ++kk) {
                    const int off = (kk - 4) * 32;
                    s8v a0 = *(const s8v*)(ph00 + off);
                    s8v a1 = *(const s8v*)(ph10 + off);
                    #pragma unroll
                    for (int f = 0; f < 4; ++f) {
                        acc[0][f] = __builtin_amdgcn_mfma_f32_16x16x32_bf16(a0, bv[kk][f], acc[0][f], 0, 0, 0);
                        acc[1][f] = __builtin_amdgcn_mfma_f32_16x16x32_bf16(a1, bv[kk][f], acc[1][f], 0, 0, 0);
                    }
                }
                // K part 3: right child h (kk 8..11, LDS B)
                #pragma unroll
                for (int kk = 8; kk < 12; ++kk) {
                    const int off = (kk - 8) * 32;
                    s8v a0 = *(const s8v*)(ph01 + off);
                    s8v a1 = *(const s8v*)(ph11 + off);
                    #pragma unroll
                    for (int f = 0; f < 4; ++f) {
                        s8v bb = *(const s8v*)(&BL[(((size_t)w * 16 + (kk - 8) * 4 + f) * 64 + lane) * 8]);
                        acc[0][f] = __builtin_amdgcn_mfma_f32_16x16x32_bf16(a0, bb, acc[0][f], 0, 0, 0);
                        acc[1][f] = __builtin_amdgcn_mfma_f32_16x16x32_bf16(a1, bb, acc[1][f], 0, 0, 0);
                    }
                }
            }
            // register-only LSTM epilogue
            #pragma unroll
            for (int mi = 0; mi < 2; ++mi) {
                #pragma unroll
                for (int r = 0; r < 4; ++r) {
                    const int m = m0 + mi * 16 + seg * 4 + r;
                    if (m < npb) {
                        const int g = start + rb + m;
                        const float gi = acc[mi][0][r] + bi;
                        const float gf = acc[mi][1][r] + bf_;
                        const float gg = acc[mi][2][r] + bg;
                        const float go = acc[mi][3][r] + bo;
                        const float c0 = leaf_lvl ? 0.0f : c_all[(size_t)g * 128 + j];
                        const float cn = sigf(gf) * c0 + sigf(gi) * tanh_fast(gg);
                        const float hn = sigf(go) * tanh_fast(cn);
                        h_all[(size_t)g * 128 + j] = f2bf(hn);
                        if (g & 1) c_all[(size_t)((g - 1) >> 1) * 128 + j] = cn;
                    }
                }
            }
        }
        __syncthreads();
    }

    if (HEAD && blockIdx.x == 0) {
        if (tid < 128) hs[tid] = bf2f(h_all[tid]);
        __syncthreads();
        if (tid < 128) {
            float a1 = b1[tid];
            #pragma unroll 4
            for (int k = 0; k < 128; ++k) a1 = fmaf(hs[k], W1[tid * 128 + k], a1);
            as[tid] = fmaxf(a1, 0.0f);
        }
        __syncthreads();
        if (tid < 32) {
            float l = b2[tid];
            #pragma unroll 4
            for (int k = 0; k < 128; ++k) l = fmaf(as[k], W2[tid * 128 + k], l);
            l = (l + logf(vmask[tid])) * (1.0f / 3.0f);
            float mx = l;
            #pragma unroll
            for (int o = 16; o >= 1; o >>= 1) mx = fmaxf(mx, __shfl_xor(mx, o, 32));
            const float e = __expf(l - mx);
            float s = e;
            #pragma unroll
            for (int o = 16; o >= 1; o >>= 1) s += __shfl_xor(s, o, 32);
            out[tid] = e / s;
        }
    }
}

extern "C" void kernel_launch(void* const* d_in, const int* in_sizes, int n_in,
                              void* d_out, int out_size, void* d_ws, size_t ws_size,
                              hipStream_t stream)
{
    const int*   node_types = (const int*)  d_in[0];
    const float* node_args  = (const float*)d_in[1];
    const float* vmask      = (const float*)d_in[2];
    const float* emb        = (const float*)d_in[3];
    const float* Wih        = (const float*)d_in[4];
    const float* Whh        = (const float*)d_in[5];
    const float* bih        = (const float*)d_in[6];
    const float* bhh        = (const float*)d_in[7];
    const float* W1         = (const float*)d_in[8];
    const float* b1         = (const float*)d_in[9];
    const float* W2         = (const float*)d_in[10];
    const float* b2         = (const float*)d_in[11];

    char* w = (char*)d_ws;
    ushort* xall  = (ushort*)(w);                 // 65536*128*2 = 16,777,216
    ushort* Bpack = (ushort*)(w + 16777216);      // 393,216
    float*  bsum  = (float*) (w + 17170432);      // 2,048
    ushort* h_all = (ushort*)(w + 17172480);      // 65536*128*2 = 16,777,216
    float*  c_all = (float*) (w + 33949696);      // 32768*128*4 = 16,777,216

    float* out = (float*)d_out;

    prepass<<<4096, 256, 0, stream>>>(node_types, node_args, emb,
                                      Wih, Whh, bih, bhh, Bpack, bsum, xall);

    quad<true,  false><<<256, 512, 0, stream>>>(xall, Bpack, bsum, h_all, c_all, 15,
                                                W1, b1, W2, b2, vmask, out);
    quad<false, false><<<8,   512, 0, stream>>>(xall, Bpack, bsum, h_all, c_all, 11,
                                                W1, b1, W2, b2, vmask, out);
    quad<false, false><<<1,   512, 0, stream>>>(xall, Bpack, bsum, h_all, c_all, 7,
                                                W1, b1, W2, b2, vmask, out);
    quad<false, true ><<<1,   512, 0, stream>>>(xall, Bpack, bsum, h_all, c_all, 3,
                                                W1, b1, W2, b2, vmask, out);
}

// Round 10
// 242.451 us; speedup vs baseline: 1.3227x; 1.2909x over previous
//
#include <hip/hip_runtime.h>
#include <hip/hip_bf16.h>

typedef __attribute__((ext_vector_type(8))) short s8v;   // 8 x bf16
typedef __attribute__((ext_vector_type(4))) float f32x4; // MFMA acc

__device__ __forceinline__ float sigf(float x) { return 1.0f / (1.0f + __expf(-x)); }
__device__ __forceinline__ float tanh_fast(float x) { return 1.0f - 2.0f / (1.0f + __expf(2.0f * x)); }
__device__ __forceinline__ ushort f2bf(float f) {
    union { __hip_bfloat16 b; ushort u; } v; v.b = __float2bfloat16(f); return v.u;
}
__device__ __forceinline__ float bf2f(ushort u) {
    union { float f; unsigned int i; } v; v.i = ((unsigned int)u) << 16; return v.f;
}

// ---------------- prepass: pack weights + fused bias + bf16 embedding gather ----------------
// Bpack: (((bn*12 + kk)*4 + seg)*128 + nl)*8 + t, col order nl -> g=(nl>>4)&3,
// j = bn*32 + (nl>>6)*16 + (nl&15)  => after MFMA each lane holds all 4 gates of one j.
__global__ __launch_bounds__(256) void prepass(
    const int* __restrict__ nt, const float* __restrict__ na,
    const float* __restrict__ emb,
    const float* __restrict__ Wih, const float* __restrict__ Whh,
    const float* __restrict__ bih, const float* __restrict__ bhh,
    ushort* __restrict__ Bpack, float* __restrict__ bsum,
    ushort* __restrict__ xall)
{
    const int gid = blockIdx.x * 256 + threadIdx.x;
    if (gid < 24576) {
        const int nl  = gid & 127;
        const int seg = (gid >> 7) & 3;
        const int rest = gid >> 9;
        const int kk = rest % 12;
        const int bn = rest / 12;
        const int g  = (nl >> 4) & 3;
        const int j  = bn * 32 + ((nl >> 6) << 4) + (nl & 15);
        const int row = g * 256 + j;
        const int k = kk * 32 + seg * 8;
        const float* src = (k < 128) ? (Wih + (size_t)row * 128 + k)
                                     : (Whh + (size_t)row * 256 + (k - 128));
        float4 w0 = *(const float4*)(src);
        float4 w1 = *(const float4*)(src + 4);
        ushort o[8] = { f2bf(w0.x), f2bf(w0.y), f2bf(w0.z), f2bf(w0.w),
                        f2bf(w1.x), f2bf(w1.y), f2bf(w1.z), f2bf(w1.w) };
        *(s8v*)(Bpack + (size_t)gid * 8) = *(const s8v*)o;
    }
    if (gid < 512) {
        const int row = (gid >> 7) * 256 + (gid & 127);
        bsum[gid] = bih[row] + bhh[row];
    }
    const int node = gid >> 4;
    const int run  = gid & 15;
    if (node < 65535) {
        const int ty = nt[node];
        const float* src = emb + (size_t)ty * 128 + run * 8;
        float4 w0 = *(const float4*)src;
        float4 w1 = *(const float4*)(src + 4);
        if (run == 15 && (ty == 1 || ty == 2)) w1.w = na[node];
        ushort o[8] = { f2bf(w0.x), f2bf(w0.y), f2bf(w0.z), f2bf(w0.w),
                        f2bf(w1.x), f2bf(w1.y), f2bf(w1.z), f2bf(w1.w) };
        *(s8v*)(xall + (size_t)node * 128 + run * 8) = *(const s8v*)o;
    }
}

#define MFMA_(a, b, c) __builtin_amdgcn_mfma_f32_16x16x32_bf16(a, b, c, 0, 0, 0)

#define DECLB(K) s8v bv##K##0, bv##K##1, bv##K##2, bv##K##3
#define LOADB(K) do { \
    bv##K##0 = *(const s8v*)(pb + K * 4096 +   0); \
    bv##K##1 = *(const s8v*)(pb + K * 4096 + 128); \
    bv##K##2 = *(const s8v*)(pb + K * 4096 + 256); \
    bv##K##3 = *(const s8v*)(pb + K * 4096 + 384); } while (0)

#define STEPV(K) do { \
    acc00 = MFMA_(a0, bv##K##0, acc00); acc10 = MFMA_(a1, bv##K##0, acc10); \
    acc01 = MFMA_(a0, bv##K##1, acc01); acc11 = MFMA_(a1, bv##K##1, acc11); \
    acc02 = MFMA_(a0, bv##K##2, acc02); acc12 = MFMA_(a1, bv##K##2, acc12); \
    acc03 = MFMA_(a0, bv##K##3, acc03); acc13 = MFMA_(a1, bv##K##3, acc13); } while (0)

#define STEPL(Q) do { \
    const s8v bb0 = *(const s8v*)(BL + (size_t)(((w * 4 + Q) * 4 + 0) * 64 + lane) * 8); \
    const s8v bb1 = *(const s8v*)(BL + (size_t)(((w * 4 + Q) * 4 + 1) * 64 + lane) * 8); \
    const s8v bb2 = *(const s8v*)(BL + (size_t)(((w * 4 + Q) * 4 + 2) * 64 + lane) * 8); \
    const s8v bb3 = *(const s8v*)(BL + (size_t)(((w * 4 + Q) * 4 + 3) * 64 + lane) * 8); \
    acc00 = MFMA_(a0, bb0, acc00); acc10 = MFMA_(a1, bb0, acc10); \
    acc01 = MFMA_(a0, bb1, acc01); acc11 = MFMA_(a1, bb1, acc11); \
    acc02 = MFMA_(a0, bb2, acc02); acc12 = MFMA_(a1, bb2, acc12); \
    acc03 = MFMA_(a0, bb3, acc03); acc13 = MFMA_(a1, bb3, acc13); } while (0)

#define EPI(MI, R) do { \
    const int m = m0 + MI * 16 + seg * 4 + R; \
    if (m < npb) { \
        const int g = start + rb + m; \
        const float gi = acc##MI##0[R] + bi; \
        const float gf = acc##MI##1[R] + bf_; \
        const float gg = acc##MI##2[R] + bg; \
        const float go = acc##MI##3[R] + bo; \
        const float c0v = leaf_lvl ? 0.0f : c_all[(size_t)g * 128 + j]; \
        const float cn = sigf(gf) * c0v + sigf(gi) * tanh_fast(gg); \
        const float hn = sigf(go) * tanh_fast(cn); \
        h_all[(size_t)g * 128 + j] = f2bf(hn); \
        if (g & 1) c_all[(size_t)((g - 1) >> 1) * 128 + j] = cn; \
    } } while (0)

// ---------------- multi-level kernel, B resident (128 VGPR named + 128KB LDS) ----------------
// 8 waves, wave w owns cols (bn=w>>1, wn=w&1): 16 j x 4 gates. All waves cover the same rows.
// Block b owns subtree rows [b*npb, (b+1)*npb) per level; children always in-block (heap h_all/c_all).
template<bool LEAF, bool HEAD>
__global__ __launch_bounds__(512) void levels_kernel(
    const ushort* __restrict__ xall,
    const ushort* __restrict__ Bpack, const float* __restrict__ bsum,
    ushort* __restrict__ h_all, float* __restrict__ c_all,
    int lvl_top, int nlv,
    const float* __restrict__ W1, const float* __restrict__ b1,
    const float* __restrict__ W2, const float* __restrict__ b2,
    const float* __restrict__ vmask, float* __restrict__ out)
{
    __shared__ __align__(16) ushort BL[65536];   // 128 KB: kk 8..11, [w][q][f][lane][8]
    __shared__ float hs[128];
    __shared__ float as[128];

    const int tid  = threadIdx.x;
    const int lane = tid & 63;
    const int w    = tid >> 6;
    const int bn = w >> 1, wn = w & 1;
    const int lc = lane & 15, seg = lane >> 4;
    const int koff = seg * 8;

    const ushort* pb = Bpack + (size_t)bn * 49152 + (size_t)seg * 1024
                             + (size_t)(wn * 64 + lc) * 8;

    // B resident: kk 0..7 named VGPRs (128 regs)
    DECLB(0); DECLB(1); DECLB(2); DECLB(3);
    DECLB(4); DECLB(5); DECLB(6); DECLB(7);
    LOADB(0); LOADB(1); LOADB(2); LOADB(3);
    LOADB(4); LOADB(5); LOADB(6); LOADB(7);
    // kk 8..11 -> LDS
    #pragma unroll
    for (int q = 0; q < 4; ++q)
        #pragma unroll
        for (int f = 0; f < 4; ++f) {
            s8v t = *(const s8v*)(pb + (size_t)(8 + q) * 4096 + f * 128);
            *(s8v*)(BL + (size_t)(((w * 4 + q) * 4 + f) * 64 + lane) * 8) = t;
        }
    __syncthreads();

    const int j = bn * 32 + wn * 16 + lc;
    const float bi  = bsum[j];
    const float bf_ = bsum[128 + j];
    const float bg  = bsum[256 + j];
    const float bo  = bsum[384 + j];

    for (int li = 0; li < nlv; ++li) {
        const int L = lvl_top - li;
        const int n_l = 1 << L;
        const int start = n_l - 1;
        int npb = n_l / (int)gridDim.x;
        if (npb < 1) npb = 1;
        const int rb = blockIdx.x * npb;
        const bool leaf_lvl = LEAF && (li == 0);

        for (int m0 = 0; m0 < npb; m0 += 32) {
            int g0, g1;
            { int mA = m0 + lc;      if (mA > npb - 1) mA = npb - 1; g0 = start + rb + mA; }
            { int mA = m0 + 16 + lc; if (mA > npb - 1) mA = npb - 1; g1 = start + rb + mA; }
            const ushort* px0 = xall + (size_t)g0 * 128 + koff;
            const ushort* px1 = xall + (size_t)g1 * 128 + koff;

            f32x4 acc00 = {0.f,0.f,0.f,0.f}, acc01 = {0.f,0.f,0.f,0.f};
            f32x4 acc02 = {0.f,0.f,0.f,0.f}, acc03 = {0.f,0.f,0.f,0.f};
            f32x4 acc10 = {0.f,0.f,0.f,0.f}, acc11 = {0.f,0.f,0.f,0.f};
            f32x4 acc12 = {0.f,0.f,0.f,0.f}, acc13 = {0.f,0.f,0.f,0.f};

            s8v a0, a1;
            a0 = *(const s8v*)(px0 +  0); a1 = *(const s8v*)(px1 +  0); STEPV(0);
            a0 = *(const s8v*)(px0 + 32); a1 = *(const s8v*)(px1 + 32); STEPV(1);
            a0 = *(const s8v*)(px0 + 64); a1 = *(const s8v*)(px1 + 64); STEPV(2);
            a0 = *(const s8v*)(px0 + 96); a1 = *(const s8v*)(px1 + 96); STEPV(3);

            if (!leaf_lvl) {
                const ushort* pl0 = h_all + (size_t)(2 * g0 + 1) * 128 + koff;
                const ushort* pl1 = h_all + (size_t)(2 * g1 + 1) * 128 + koff;
                const ushort* pr0 = h_all + (size_t)(2 * g0 + 2) * 128 + koff;
                const ushort* pr1 = h_all + (size_t)(2 * g1 + 2) * 128 + koff;
                a0 = *(const s8v*)(pl0 +  0); a1 = *(const s8v*)(pl1 +  0); STEPV(4);
                a0 = *(const s8v*)(pl0 + 32); a1 = *(const s8v*)(pl1 + 32); STEPV(5);
                a0 = *(const s8v*)(pl0 + 64); a1 = *(const s8v*)(pl1 + 64); STEPV(6);
                a0 = *(const s8v*)(pl0 + 96); a1 = *(const s8v*)(pl1 + 96); STEPV(7);
                a0 = *(const s8v*)(pr0 +  0); a1 = *(const s8v*)(pr1 +  0); STEPL(0);
                a0 = *(const s8v*)(pr0 + 32); a1 = *(const s8v*)(pr1 + 32); STEPL(1);
                a0 = *(const s8v*)(pr0 + 64); a1 = *(const s8v*)(pr1 + 64); STEPL(2);
                a0 = *(const s8v*)(pr0 + 96); a1 = *(const s8v*)(pr1 + 96); STEPL(3);
            }

            EPI(0, 0); EPI(0, 1); EPI(0, 2); EPI(0, 3);
            EPI(1, 0); EPI(1, 1); EPI(1, 2); EPI(1, 3);
        }
        __syncthreads();
    }

    if (HEAD && blockIdx.x == 0) {
        if (tid < 128) hs[tid] = bf2f(h_all[tid]);
        __syncthreads();
        if (tid < 128) {
            float a1h = b1[tid];
            #pragma unroll 4
            for (int k = 0; k < 128; ++k) a1h = fmaf(hs[k], W1[tid * 128 + k], a1h);
            as[tid] = fmaxf(a1h, 0.0f);
        }
        __syncthreads();
        if (tid < 32) {
            float l = b2[tid];
            #pragma unroll 4
            for (int k = 0; k < 128; ++k) l = fmaf(as[k], W2[tid * 128 + k], l);
            l = (l + logf(vmask[tid])) * (1.0f / 3.0f);
            float mx = l;
            #pragma unroll
            for (int o = 16; o >= 1; o >>= 1) mx = fmaxf(mx, __shfl_xor(mx, o, 32));
            const float e = __expf(l - mx);
            float s = e;
            #pragma unroll
            for (int o = 16; o >= 1; o >>= 1) s += __shfl_xor(s, o, 32);
            out[tid] = e / s;
        }
    }
}

extern "C" void kernel_launch(void* const* d_in, const int* in_sizes, int n_in,
                              void* d_out, int out_size, void* d_ws, size_t ws_size,
                              hipStream_t stream)
{
    const int*   node_types = (const int*)  d_in[0];
    const float* node_args  = (const float*)d_in[1];
    const float* vmask      = (const float*)d_in[2];
    const float* emb        = (const float*)d_in[3];
    const float* Wih        = (const float*)d_in[4];
    const float* Whh        = (const float*)d_in[5];
    const float* bih        = (const float*)d_in[6];
    const float* bhh        = (const float*)d_in[7];
    const float* W1         = (const float*)d_in[8];
    const float* b1         = (const float*)d_in[9];
    const float* W2         = (const float*)d_in[10];
    const float* b2         = (const float*)d_in[11];

    char* w = (char*)d_ws;
    ushort* xall  = (ushort*)(w);                 // 65536*128*2 = 16,777,216
    ushort* Bpack = (ushort*)(w + 16777216);      // 393,216
    float*  bsum  = (float*) (w + 17170432);      // 2,048
    ushort* h_all = (ushort*)(w + 17172480);      // 65536*128*2 = 16,777,216
    float*  c_all = (float*) (w + 33949696);      // 32768*128*4 = 16,777,216

    float* out = (float*)d_out;

    prepass<<<4096, 256, 0, stream>>>(node_types, node_args, emb,
                                      Wih, Whh, bih, bhh, Bpack, bsum, xall);

    levels_kernel<true,  false><<<256, 512, 0, stream>>>(
        xall, Bpack, bsum, h_all, c_all, 15, 4, W1, b1, W2, b2, vmask, out);
    levels_kernel<false, false><<<16,  512, 0, stream>>>(
        xall, Bpack, bsum, h_all, c_all, 11, 4, W1, b1, W2, b2, vmask, out);
    levels_kernel<false, true ><<<1,   512, 0, stream>>>(
        xall, Bpack, bsum, h_all, c_all, 7, 8, W1, b1, W2, b2, vmask, out);
}